// Round 2
// baseline (230.601 us; speedup 1.0000x reference)
//
#include <hip/hip_runtime.h>
#include <stdint.h>
#include <stddef.h>

#define MDIM 2048
#define KDIM 4096
#define NDIM 4096
// group size G = 128 along K

using bf16x8 = __attribute__((ext_vector_type(8))) short;   // 8 bf16 bit-patterns
using f32x4  = __attribute__((ext_vector_type(4))) float;   // MFMA accumulator
using short8 = __attribute__((ext_vector_type(8))) short;

// fp32 -> bf16 (round-to-nearest-even), bit pattern in short
__device__ __forceinline__ short f2bf(float f) {
    union { float f; uint32_t u; } v; v.f = f;
    return (short)((v.u + 0x7fffu + ((v.u >> 16) & 1u)) >> 16);
}

// ---------------------------------------------------------------------------
// Fused prep, one dispatch:
//   blocks [0,4096):       cast x (M,K) fp32 -> bf16           (48 MB traffic)
//   blocks [4096,12288):   dequant int4 -> bf16 W (N,K)        (40 MB traffic)
//   blocks [12288,20480):  zero d_out (atomic split-K target)  (32 MB traffic)
// ---------------------------------------------------------------------------
__global__ __launch_bounds__(256) void prep(const float* __restrict__ x,
                                            const int* __restrict__ Bq,
                                            const float* __restrict__ s,
                                            short* __restrict__ xbf,
                                            short* __restrict__ wbf,
                                            float* __restrict__ out) {
    const int b = blockIdx.x, tid = threadIdx.x;
    if (b < 4096) {
        int i = (b * 256 + tid) * 8;
        float4 a = *(const float4*)(x + i);
        float4 c = *(const float4*)(x + i + 4);
        short8 o;
        o[0] = f2bf(a.x); o[1] = f2bf(a.y); o[2] = f2bf(a.z); o[3] = f2bf(a.w);
        o[4] = f2bf(c.x); o[5] = f2bf(c.y); o[6] = f2bf(c.z); o[7] = f2bf(c.w);
        *(short8*)(xbf + i) = o;
    } else if (b < 12288) {
        int t  = (b - 4096) * 256 + tid;
        int kc = t & 511;              // K/8 chunks per output row
        int n  = t >> 9;
        int k0 = kc * 8;
        int sh = (n & 7) * 4;
        const int* brow = Bq + (size_t)(n >> 3) * KDIM + k0;
        float sc = s[(k0 >> 7) * NDIM + n];
        int4 p0 = *(const int4*)(brow);
        int4 p1 = *(const int4*)(brow + 4);
        short8 o;
        o[0] = f2bf((float)(((p0.x >> sh) & 0xF) - 8) * sc);
        o[1] = f2bf((float)(((p0.y >> sh) & 0xF) - 8) * sc);
        o[2] = f2bf((float)(((p0.z >> sh) & 0xF) - 8) * sc);
        o[3] = f2bf((float)(((p0.w >> sh) & 0xF) - 8) * sc);
        o[4] = f2bf((float)(((p1.x >> sh) & 0xF) - 8) * sc);
        o[5] = f2bf((float)(((p1.y >> sh) & 0xF) - 8) * sc);
        o[6] = f2bf((float)(((p1.z >> sh) & 0xF) - 8) * sc);
        o[7] = f2bf((float)(((p1.w >> sh) & 0xF) - 8) * sc);
        *(short8*)(wbf + (size_t)n * KDIM + k0) = o;
    } else {
        int i = ((b - 12288) * 256 + tid) * 4;
        *(float4*)(out + i) = float4{0.f, 0.f, 0.f, 0.f};
    }
}

// ---------------------------------------------------------------------------
// Split-K bf16 GEMM: C += A(2048x4096) * W(4096x4096)^T over K-half per
// blockIdx.z.  128x128 tile, BK=32, 4 waves (2x2) of 64x64, 4x4 16x16x32
// MFMA, global_load_lds width=16, atomic fp32 epilogue.
//
// LDS swizzle (bank-conflict fix): chunk (row r, kchunk q) lives at slot
// r*4 + ((q + (r>>1)) & 3).  Staging inverts on the global source address
// (per-lane vaddr, contiguous LDS dest — global_load_lds compatible).
// Read side: 8 consecutive lanes hit 8 distinct 4-bank groups -> no conflict.
// C/D layout: col = lane&15, row = (lane>>4)*4 + reg  (m89/m91 verified).
// ---------------------------------------------------------------------------
__global__ __launch_bounds__(256) void gemm_splitk(const short* __restrict__ A,
                                                   const short* __restrict__ W,
                                                   float* __restrict__ C) {
    __shared__ __align__(16) short As[128 * 32];
    __shared__ __align__(16) short Ws[128 * 32];

    const int tid  = threadIdx.x;
    const int lane = tid & 63;
    const int wave = tid >> 6;
    const int bm = blockIdx.y * 128;
    const int bn = blockIdx.x * 128;
    const int kz = blockIdx.z * (KDIM / 2);
    const int wm = (wave >> 1) * 64;
    const int wn = (wave & 1) * 64;

    // staging: thread fills LDS slots s0=tid, s1=tid+256 (16 B each, contiguous)
    const int s0 = tid, s1 = tid + 256;
    const int r0 = s0 >> 2, q0 = ((s0 & 3) - (r0 >> 1)) & 3;
    const int r1 = s1 >> 2, q1 = ((s1 & 3) - (r1 >> 1)) & 3;
    const size_t aoff0 = (size_t)(bm + r0) * KDIM + q0 * 8 + kz;
    const size_t aoff1 = (size_t)(bm + r1) * KDIM + q1 * 8 + kz;
    const size_t woff0 = (size_t)(bn + r0) * KDIM + q0 * 8 + kz;
    const size_t woff1 = (size_t)(bn + r1) * KDIM + q1 * 8 + kz;

    const int fr  = lane & 15;                 // fragment row (m or n)
    const int qc  = lane >> 4;                 // k-chunk within BK=32
    const int swz = (qc + (fr >> 1)) & 3;      // swizzled slot column

    f32x4 acc[4][4] = {};

    for (int k0 = 0; k0 < KDIM / 2; k0 += 32) {
        __builtin_amdgcn_global_load_lds(
            (const __attribute__((address_space(1))) uint32_t*)(A + aoff0 + k0),
            (__attribute__((address_space(3))) uint32_t*)(&As[s0 * 8]), 16, 0, 0);
        __builtin_amdgcn_global_load_lds(
            (const __attribute__((address_space(1))) uint32_t*)(A + aoff1 + k0),
            (__attribute__((address_space(3))) uint32_t*)(&As[s1 * 8]), 16, 0, 0);
        __builtin_amdgcn_global_load_lds(
            (const __attribute__((address_space(1))) uint32_t*)(W + woff0 + k0),
            (__attribute__((address_space(3))) uint32_t*)(&Ws[s0 * 8]), 16, 0, 0);
        __builtin_amdgcn_global_load_lds(
            (const __attribute__((address_space(1))) uint32_t*)(W + woff1 + k0),
            (__attribute__((address_space(3))) uint32_t*)(&Ws[s1 * 8]), 16, 0, 0);
        __syncthreads();

        bf16x8 af[4], bfv[4];
#pragma unroll
        for (int i = 0; i < 4; i++)
            af[i] = *(const bf16x8*)&As[(wm + i * 16 + fr) * 32 + swz * 8];
#pragma unroll
        for (int j = 0; j < 4; j++)
            bfv[j] = *(const bf16x8*)&Ws[(wn + j * 16 + fr) * 32 + swz * 8];
#pragma unroll
        for (int i = 0; i < 4; i++)
#pragma unroll
            for (int j = 0; j < 4; j++)
                acc[i][j] = __builtin_amdgcn_mfma_f32_16x16x32_bf16(
                    af[i], bfv[j], acc[i][j], 0, 0, 0);
        __syncthreads();
    }

    // epilogue: atomic accumulate both K-halves into zero-inited C
    const int col = bn + wn + fr;
    const int rr  = (lane >> 4) * 4;
#pragma unroll
    for (int i = 0; i < 4; i++)
#pragma unroll
        for (int j = 0; j < 4; j++)
#pragma unroll
            for (int r = 0; r < 4; r++)
                unsafeAtomicAdd(&C[(size_t)(bm + wm + i * 16 + rr + r) * NDIM
                                   + (col + j * 16)],
                                acc[i][j][r]);
}

// ---------------------------------------------------------------------------
extern "C" void kernel_launch(void* const* d_in, const int* in_sizes, int n_in,
                              void* d_out, int out_size, void* d_ws, size_t ws_size,
                              hipStream_t stream) {
    const float* x  = (const float*)d_in[0];
    const int*   Bq = (const int*)d_in[1];
    const float* s  = (const float*)d_in[2];
    float* out = (float*)d_out;

    // workspace: [0,16MB) x in bf16, [16MB,48MB) dequantized W in bf16
    short* xbf = (short*)d_ws;
    short* wbf = xbf + (size_t)MDIM * KDIM;

    hipLaunchKernelGGL(prep, dim3(20480), dim3(256), 0, stream,
                       x, Bq, s, xbf, wbf, out);
    hipLaunchKernelGGL(gemm_splitk, dim3(NDIM / 128, MDIM / 128, 2), dim3(256),
                       0, stream, xbf, wbf, out);
}

// Round 3
// 191.159 us; speedup vs baseline: 1.2063x; 1.2063x over previous
//
#include <hip/hip_runtime.h>
#include <stdint.h>
#include <stddef.h>

#define MDIM 2048
#define KDIM 4096
#define NDIM 4096
// group size G = 128 along K

using bf16x8 = __attribute__((ext_vector_type(8))) short;   // 8 bf16 bit-patterns
using f32x4  = __attribute__((ext_vector_type(4))) float;   // MFMA accumulator
using short8 = __attribute__((ext_vector_type(8))) short;

// fp32 -> bf16 (round-to-nearest-even), bit pattern in short
__device__ __forceinline__ short f2bf(float f) {
    union { float f; uint32_t u; } v; v.f = f;
    return (short)((v.u + 0x7fffu + ((v.u >> 16) & 1u)) >> 16);
}

// ---------------------------------------------------------------------------
// Fused prep, one dispatch:
//   blocks [0,4096):      cast x (M,K) fp32 -> bf16       (48 MB traffic)
//   blocks [4096,12288):  dequant int4 -> bf16 W (N,K)    (40 MB traffic)
// ---------------------------------------------------------------------------
__global__ __launch_bounds__(256) void prep(const float* __restrict__ x,
                                            const int* __restrict__ Bq,
                                            const float* __restrict__ s,
                                            short* __restrict__ xbf,
                                            short* __restrict__ wbf) {
    const int b = blockIdx.x, tid = threadIdx.x;
    if (b < 4096) {
        int i = (b * 256 + tid) * 8;
        float4 a = *(const float4*)(x + i);
        float4 c = *(const float4*)(x + i + 4);
        short8 o;
        o[0] = f2bf(a.x); o[1] = f2bf(a.y); o[2] = f2bf(a.z); o[3] = f2bf(a.w);
        o[4] = f2bf(c.x); o[5] = f2bf(c.y); o[6] = f2bf(c.z); o[7] = f2bf(c.w);
        *(short8*)(xbf + i) = o;
    } else {
        int t  = (b - 4096) * 256 + tid;
        int kc = t & 511;              // K/8 chunks per output row
        int n  = t >> 9;
        int k0 = kc * 8;
        int sh = (n & 7) * 4;
        const int* brow = Bq + (size_t)(n >> 3) * KDIM + k0;
        float sc = s[(k0 >> 7) * NDIM + n];
        int4 p0 = *(const int4*)(brow);
        int4 p1 = *(const int4*)(brow + 4);
        short8 o;
        o[0] = f2bf((float)(((p0.x >> sh) & 0xF) - 8) * sc);
        o[1] = f2bf((float)(((p0.y >> sh) & 0xF) - 8) * sc);
        o[2] = f2bf((float)(((p0.z >> sh) & 0xF) - 8) * sc);
        o[3] = f2bf((float)(((p0.w >> sh) & 0xF) - 8) * sc);
        o[4] = f2bf((float)(((p1.x >> sh) & 0xF) - 8) * sc);
        o[5] = f2bf((float)(((p1.y >> sh) & 0xF) - 8) * sc);
        o[6] = f2bf((float)(((p1.z >> sh) & 0xF) - 8) * sc);
        o[7] = f2bf((float)(((p1.w >> sh) & 0xF) - 8) * sc);
        *(short8*)(wbf + (size_t)n * KDIM + k0) = o;
    }
}

// ---------------------------------------------------------------------------
// bf16 GEMM: C = A(2048x4096) * W(4096x4096)^T, fp32 out.
// Tile 128(M) x 64(N), BK=32, 256 threads = 4 waves (2x2), wave tile 64x32,
// 4x2 16x16x32 MFMA per wave.  Grid 64x16 = 1024 blocks -> 4 blocks/CU,
// 16 waves/CU: independent blocks cover each other's barrier drains
// (no atomics, disjoint outputs).
//
// LDS swizzle (verified conflict-free in R2): chunk (row r, kchunk q) lives
// at slot r*4 + ((q + (r>>1)) & 3); staging inverts on the per-lane global
// source address, LDS dest stays lane-contiguous (global_load_lds-legal).
// C/D layout: col = lane&15, row = (lane>>4)*4 + reg  (m89/m91 verified).
// ---------------------------------------------------------------------------
__global__ __launch_bounds__(256, 4) void gemm_bf16(const short* __restrict__ A,
                                                    const short* __restrict__ W,
                                                    float* __restrict__ C) {
    __shared__ __align__(16) short As[128 * 32];   // 8 KB
    __shared__ __align__(16) short Ws[64 * 32];    // 4 KB

    const int tid  = threadIdx.x;
    const int lane = tid & 63;
    const int wave = tid >> 6;
    const int bm = blockIdx.y * 128;
    const int bn = blockIdx.x * 64;
    const int wm = (wave >> 1) * 64;   // wave M-offset in tile
    const int wn = (wave & 1) * 32;    // wave N-offset in tile

    // staging slots: A gets s0=tid, s1=tid+256 (512 chunks); W gets sw=tid.
    const int s0 = tid, s1 = tid + 256, sw = tid;
    const int ra0 = s0 >> 2, qa0 = ((s0 & 3) - (ra0 >> 1)) & 3;
    const int ra1 = s1 >> 2, qa1 = ((s1 & 3) - (ra1 >> 1)) & 3;
    const int rw  = sw >> 2, qw  = ((sw & 3) - (rw >> 1)) & 3;
    const size_t aoff0 = (size_t)(bm + ra0) * KDIM + qa0 * 8;
    const size_t aoff1 = (size_t)(bm + ra1) * KDIM + qa1 * 8;
    const size_t woff  = (size_t)(bn + rw)  * KDIM + qw * 8;

    const int fr  = lane & 15;                 // fragment row (m or n)
    const int qc  = lane >> 4;                 // k-chunk within BK=32
    const int swz = (qc + (fr >> 1)) & 3;      // swizzled slot column

    f32x4 acc[4][2] = {};

    for (int k0 = 0; k0 < KDIM; k0 += 32) {
        __builtin_amdgcn_global_load_lds(
            (const __attribute__((address_space(1))) uint32_t*)(A + aoff0 + k0),
            (__attribute__((address_space(3))) uint32_t*)(&As[s0 * 8]), 16, 0, 0);
        __builtin_amdgcn_global_load_lds(
            (const __attribute__((address_space(1))) uint32_t*)(A + aoff1 + k0),
            (__attribute__((address_space(3))) uint32_t*)(&As[s1 * 8]), 16, 0, 0);
        __builtin_amdgcn_global_load_lds(
            (const __attribute__((address_space(1))) uint32_t*)(W + woff + k0),
            (__attribute__((address_space(3))) uint32_t*)(&Ws[sw * 8]), 16, 0, 0);
        __syncthreads();

        bf16x8 af[4], bfv[2];
#pragma unroll
        for (int i = 0; i < 4; i++)
            af[i] = *(const bf16x8*)&As[(wm + i * 16 + fr) * 32 + swz * 8];
#pragma unroll
        for (int j = 0; j < 2; j++)
            bfv[j] = *(const bf16x8*)&Ws[(wn + j * 16 + fr) * 32 + swz * 8];
#pragma unroll
        for (int i = 0; i < 4; i++)
#pragma unroll
            for (int j = 0; j < 2; j++)
                acc[i][j] = __builtin_amdgcn_mfma_f32_16x16x32_bf16(
                    af[i], bfv[j], acc[i][j], 0, 0, 0);
        __syncthreads();
    }

    // epilogue: D[row = (lane>>4)*4 + r][col = lane&15], direct stores
    const int col = bn + wn + fr;
    const int rr  = (lane >> 4) * 4;
#pragma unroll
    for (int i = 0; i < 4; i++)
#pragma unroll
        for (int j = 0; j < 2; j++)
#pragma unroll
            for (int r = 0; r < 4; r++)
                C[(size_t)(bm + wm + i * 16 + rr + r) * NDIM + (col + j * 16)]
                    = acc[i][j][r];
}

// ---------------------------------------------------------------------------
extern "C" void kernel_launch(void* const* d_in, const int* in_sizes, int n_in,
                              void* d_out, int out_size, void* d_ws, size_t ws_size,
                              hipStream_t stream) {
    const float* x  = (const float*)d_in[0];
    const int*   Bq = (const int*)d_in[1];
    const float* s  = (const float*)d_in[2];
    float* out = (float*)d_out;

    // workspace: [0,16MB) x in bf16, [16MB,48MB) dequantized W in bf16
    short* xbf = (short*)d_ws;
    short* wbf = xbf + (size_t)MDIM * KDIM;

    hipLaunchKernelGGL(prep, dim3(12288), dim3(256), 0, stream,
                       x, Bq, s, xbf, wbf);
    hipLaunchKernelGGL(gemm_bf16, dim3(NDIM / 64, MDIM / 128), dim3(256),
                       0, stream, xbf, wbf, out);
}